// Round 1
// baseline (163.399 us; speedup 1.0000x reference)
//
#include <hip/hip_runtime.h>
#include <hip/hip_bf16.h>

#define N_NODES 50000
#define N_EDGES 800000
#define D 128

#define NBUCK 782        // bucket = dst>>6  (64 nodes); 49999>>6 = 781
#define BCAP  2048       // global slots/bucket; count ~1023 +/- ~32 (sd)
#define LCAP  1536       // LDS slots/bucket; mean+16sd, never trips

#define SCAT_BLOCKS ((N_EDGES / 4 + 1023) / 1024)   // 196 — covers ALL edges

using bf16x8 = __attribute__((ext_vector_type(8))) short;   // 8 bf16 (4 VGPRs)
using u16x8  = __attribute__((ext_vector_type(8))) unsigned short;
using f32x4  = __attribute__((ext_vector_type(4))) float;   // MFMA C/D

static __device__ __forceinline__ ushort f2bf(float f) {
    __hip_bfloat16 h = __float2bfloat16(f);   // RNE
    return *reinterpret_cast<ushort*>(&h);
}
static __device__ __forceinline__ float bf2f(ushort u) {
    return __uint_as_float(((unsigned)u) << 16);
}

// ---------------------------------------------------------------------------
// ws layout (~19.3 MB): bcnt[NBUCK], pairs[NBUCK*BCAP] int, xb (bf16 x).
// su16 / off2 / aggb eliminated: CSR + gather + GEMM fused per bucket.
// ---------------------------------------------------------------------------

// Fused: x -> bf16 conversion (grid-stride) + bucket scatter of edges.
__global__ void __launch_bounds__(1024)
convert_scatter(const float4* __restrict__ x4, ushort* __restrict__ xb,
                const int* __restrict__ src, const int* __restrict__ dst,
                int* __restrict__ bcnt, int* __restrict__ pairs) {
    __shared__ int lcnt[NBUCK], lbase[NBUCK];
    const int tid = threadIdx.x;
    if (tid < NBUCK) lcnt[tid] = 0;

    // issue edge loads early (latency overlapped with conversion below)
    const int i = blockIdx.x * 1024 + tid;
    const bool valid = i < N_EDGES / 4;
    int4 s, d;
    if (valid) {
        s = ((const int4*)src)[i];
        d = ((const int4*)dst)[i];
    }

    // streaming conversion: 1.6M float4, grid-stride over the actual grid
    const int total4 = N_NODES * D / 4;
    const int stride = gridDim.x * 1024;
    for (int j = blockIdx.x * 1024 + tid; j < total4; j += stride) {
        float4 v = x4[j];
        ushort4 u = make_ushort4(f2bf(v.x), f2bf(v.y), f2bf(v.z), f2bf(v.w));
        *(ushort4*)(xb + (size_t)j * 4) = u;
    }
    __syncthreads();          // lcnt zeros visible

    int bkt[4], slot[4];
    if (valid) {
        bkt[0] = d.x >> 6; slot[0] = atomicAdd(&lcnt[bkt[0]], 1);
        bkt[1] = d.y >> 6; slot[1] = atomicAdd(&lcnt[bkt[1]], 1);
        bkt[2] = d.z >> 6; slot[2] = atomicAdd(&lcnt[bkt[2]], 1);
        bkt[3] = d.w >> 6; slot[3] = atomicAdd(&lcnt[bkt[3]], 1);
    }
    __syncthreads();
    if (tid < NBUCK) {
        int c = lcnt[tid];
        lbase[tid] = c ? atomicAdd(&bcnt[tid], c) : 0;
    }
    __syncthreads();
    if (valid) {
#pragma unroll
        for (int e = 0; e < 4; ++e) {
            int sv = (e == 0) ? s.x : (e == 1) ? s.y : (e == 2) ? s.z : s.w;
            int dv = (e == 0) ? d.x : (e == 1) ? d.y : (e == 2) ? d.z : d.w;
            int pos = lbase[bkt[e]] + slot[e];
            if (pos < BCAP)                       // ~32-sd guard, never trips
                pairs[bkt[e] * BCAP + pos] = sv | ((dv & 63) << 16);
        }
    }
}

// ---------------------------------------------------------------------------
// Fused per-bucket kernel: CSR-in-LDS -> gather to LDS agg tile -> MFMA GEMM
// + relu + residual. One block per bucket (64 nodes), 256 threads (4 waves).
// LDS 54016 B => 3 blocks/CU (12 waves/CU).
//   Wl   [2048][8] bf16 chunk-major   32768 B   (W staged once per block)
//   lsrc [1536]    ushort              3072 B   (per-node-sorted src indices)
//   aggL [64][136] bf16 (pad 8)      17408 B   (agg rows; 16B-aligned rows)
//   lcnt2/lcur/lbeg [64] int each      768 B
// ---------------------------------------------------------------------------
__global__ void __launch_bounds__(256)
csr_gather_gemm(const int* __restrict__ pairs, const int* __restrict__ bcnt,
                const ushort* __restrict__ xb, const float* __restrict__ W,
                float* __restrict__ out) {
    __shared__ __align__(16) char lds[54016];
    ushort* Wl    = (ushort*)lds;                    // 32768 B
    ushort* lsrc  = (ushort*)(lds + 32768);          //  3072 B
    ushort* aggL  = (ushort*)(lds + 35840);          // 17408 B
    int*    lcnt2 = (int*)(lds + 53248);
    int*    lcur  = (int*)(lds + 53504);
    int*    lbeg  = (int*)(lds + 53760);

    const int b    = blockIdx.x;
    const int tid  = threadIdx.x;
    const int lane = tid & 63;
    const int wv   = tid >> 6;
    const int m16  = lane & 15;
    const int q    = lane >> 4;

    // ---- stage W into LDS as bf16, chunk-major [k/8][o][8] ----
#pragma unroll
    for (int i = 0; i < 8; ++i) {
        int g  = tid + i * 256;
        int o  = g & 127;
        int kc = g >> 7;
        const float4* wp = (const float4*)(W + (size_t)o * D + kc * 8);
        float4 w0 = wp[0], w1 = wp[1];
        bf16x8 hv;
        hv[0] = (short)f2bf(w0.x); hv[1] = (short)f2bf(w0.y);
        hv[2] = (short)f2bf(w0.z); hv[3] = (short)f2bf(w0.w);
        hv[4] = (short)f2bf(w1.x); hv[5] = (short)f2bf(w1.y);
        hv[6] = (short)f2bf(w1.z); hv[7] = (short)f2bf(w1.w);
        *(bf16x8*)&Wl[g * 8] = hv;
    }

    // ---- CSR in LDS: histogram -> wave-0 scan -> place ----
    const int base = b * BCAP;
    int n = bcnt[b];
    if (n > LCAP) n = LCAP;                          // 16-sd guard, never trips
    if (tid < 64) lcnt2[tid] = 0;
    __syncthreads();
    for (int i = tid; i < n; i += 256)
        atomicAdd(&lcnt2[pairs[base + i] >> 16], 1);
    __syncthreads();
    if (tid < 64) {                       // wave 0: 64-lane inclusive shfl scan
        int v = lcnt2[tid];
        int incl = v;
#pragma unroll
        for (int o = 1; o < 64; o <<= 1) {
            int t = __shfl_up(incl, o, 64);
            if (tid >= o) incl += t;
        }
        lbeg[tid] = incl - v;
        lcur[tid] = incl - v;
    }
    __syncthreads();
    for (int i = tid; i < n; i += 256) {
        int p = pairs[base + i];
        int pos = atomicAdd(&lcur[p >> 16], 1);
        lsrc[pos] = (ushort)(p & 0xFFFF);
    }
    __syncthreads();                      // lcur[t] == end(t) now

    // ---- gather: wave wv owns nodes wv*16 .. wv*16+15 (sequential) ----
    // Quarter-wave rows: 16 lanes x u16x8 (16B) = one full 256B bf16 row;
    // 4 rows/step; 4 steps in flight => 16 row-loads outstanding per wave.
    const int c8 = m16 << 3;               // bf16 col 0,8,..,120
    const ushort* xbb = xb + c8;
#pragma unroll 1
    for (int m = 0; m < 16; ++m) {
        const int node = wv * 16 + m;
        const int beg = lbeg[node], end = lcur[node];
        float acc[8];
#pragma unroll
        for (int j = 0; j < 8; ++j) acc[j] = 0.f;

        int t = beg;
        for (; t + 16 <= end; t += 16) {   // 16 rows in flight
            int s0 = lsrc[t + q];          // broadcast LDS read per quarter
            int s1 = lsrc[t + 4 + q];
            int s2 = lsrc[t + 8 + q];
            int s3 = lsrc[t + 12 + q];
            u16x8 u0 = *(const u16x8*)(xbb + (size_t)s0 * D);
            u16x8 u1 = *(const u16x8*)(xbb + (size_t)s1 * D);
            u16x8 u2 = *(const u16x8*)(xbb + (size_t)s2 * D);
            u16x8 u3 = *(const u16x8*)(xbb + (size_t)s3 * D);
#pragma unroll
            for (int j = 0; j < 8; ++j)
                acc[j] += (bf2f(u0[j]) + bf2f(u1[j])) + (bf2f(u2[j]) + bf2f(u3[j]));
        }
        for (; t + 4 <= end; t += 4) {
            int s = lsrc[t + q];
            u16x8 u = *(const u16x8*)(xbb + (size_t)s * D);
#pragma unroll
            for (int j = 0; j < 8; ++j) acc[j] += bf2f(u[j]);
        }
        const int rem = end - t;
        if (rem && q < rem) {
            int s = lsrc[t + q];
            u16x8 u = *(const u16x8*)(xbb + (size_t)s * D);
#pragma unroll
            for (int j = 0; j < 8; ++j) acc[j] += bf2f(u[j]);
        }
#pragma unroll
        for (int j = 0; j < 8; ++j) {
            acc[j] += __shfl_xor(acc[j], 16, 64);
            acc[j] += __shfl_xor(acc[j], 32, 64);
        }
        if (q == 0) {                      // row write: 16 lanes x 16B, 256B
            u16x8 u;
#pragma unroll
            for (int j = 0; j < 8; ++j) u[j] = f2bf(acc[j]);
            *(u16x8*)&aggL[(size_t)node * 136 + c8] = u;   // 272B rows, 16B-aligned
        }
    }
    __syncthreads();                       // Wl staged + aggL complete

    // ---- MFMA GEMM: out[n][o] = relu(sum_k agg[n][k]*W[o][k]) + x[n][o] ----
    bf16x8 a[4];
#pragma unroll
    for (int kb = 0; kb < 4; ++kb)
        a[kb] = *(const bf16x8*)&aggL[(size_t)(wv * 16 + m16) * 136 + kb * 32 + q * 8];

    f32x4 acc[8];
#pragma unroll
    for (int t = 0; t < 8; ++t) {
        acc[t] = (f32x4){0.f, 0.f, 0.f, 0.f};
#pragma unroll
        for (int kb = 0; kb < 4; ++kb) {
            bf16x8 bfr = *(const bf16x8*)&Wl[(((kb * 4 + q) * 128) + t * 16 + m16) * 8];
            acc[t] = __builtin_amdgcn_mfma_f32_16x16x32_bf16(a[kb], bfr, acc[t], 0, 0, 0);
        }
    }

    __syncthreads();                              // Wl/lsrc dead after this
    float* Ew = (float*)(lds + wv * 8448);        // 16 rows x 132 floats (33792B < aggL off)
#pragma unroll
    for (int t = 0; t < 8; ++t)
#pragma unroll
        for (int r = 0; r < 4; ++r)
            Ew[(q * 4 + r) * 132 + t * 16 + m16] = acc[t][r];

    const int nb = b * 64 + wv * 16;
    const int h  = lane >> 5;
    const int c4 = (lane & 31) << 2;
#pragma unroll
    for (int j = 0; j < 8; ++j) {
        int r = j * 2 + h;
        int node = nb + r;
        if (node < N_NODES) {
            float4 v  = *(const float4*)&Ew[r * 132 + c4];
            ushort4 xu = *(const ushort4*)(xb + (size_t)node * D + c4);
            float4 o;
            o.x = fmaxf(v.x, 0.f) + bf2f(xu.x);
            o.y = fmaxf(v.y, 0.f) + bf2f(xu.y);
            o.z = fmaxf(v.z, 0.f) + bf2f(xu.z);
            o.w = fmaxf(v.w, 0.f) + bf2f(xu.w);
            *(float4*)(out + (size_t)node * D + c4) = o;
        }
    }
}

// ===================== minimal fallback (tiny ws; never expected) ==========
__global__ void zero_out(float4* __restrict__ p, int n4) {
    int i = blockIdx.x * 256 + threadIdx.x;
    if (i < n4) p[i] = make_float4(0.f, 0.f, 0.f, 0.f);
}
__global__ void scatter_edges(const float* __restrict__ x,
                              const int* __restrict__ src,
                              const int* __restrict__ dst,
                              float* __restrict__ agg) {
    long long tid = (long long)blockIdx.x * 256 + threadIdx.x;
    if (tid >= (long long)N_EDGES * 32) return;
    int edge = (int)(tid >> 5);
    int c    = ((int)tid & 31) << 2;
    const float4 v = *(const float4*)(x + (size_t)src[edge] * D + c);
    float* p = agg + (size_t)dst[edge] * D + c;
    unsafeAtomicAdd(p + 0, v.x);
    unsafeAtomicAdd(p + 1, v.y);
    unsafeAtomicAdd(p + 2, v.z);
    unsafeAtomicAdd(p + 3, v.w);
}
__global__ void __launch_bounds__(256)
gemm_relu_res_f32(float* data, const float* __restrict__ W,
                  const float* __restrict__ x) {
    __shared__ __align__(16) char lds[50176];
    ushort* Wl = (ushort*)lds;
    ushort* Al = (ushort*)(lds + 32768);
    const int tid  = threadIdx.x;
    const int lane = tid & 63;
    const int wv   = tid >> 6;
    const int m16  = lane & 15;
    const int q    = lane >> 4;
#pragma unroll
    for (int i = 0; i < 8; ++i) {
        int g  = tid + i * 256;
        int o  = g & 127;
        int kc = g >> 7;
        const float4* wp = (const float4*)(W + (size_t)o * D + kc * 8);
        float4 w0 = wp[0], w1 = wp[1];
        bf16x8 hv;
        hv[0] = (short)f2bf(w0.x); hv[1] = (short)f2bf(w0.y);
        hv[2] = (short)f2bf(w0.z); hv[3] = (short)f2bf(w0.w);
        hv[4] = (short)f2bf(w1.x); hv[5] = (short)f2bf(w1.y);
        hv[6] = (short)f2bf(w1.z); hv[7] = (short)f2bf(w1.w);
        *(bf16x8*)&Wl[g * 8] = hv;
    }
    __syncthreads();
    const int nb = blockIdx.x * 64 + wv * 16;
    ushort* Aw = &Al[wv * (16 * 136)];
#pragma unroll
    for (int m = 0; m < 16; ++m) {
        int node = nb + m;
        float2 v = make_float2(0.f, 0.f);
        if (node < N_NODES)
            v = *(const float2*)(data + (size_t)node * D + lane * 2);
        *(ushort2*)&Aw[m * 136 + lane * 2] = make_ushort2(f2bf(v.x), f2bf(v.y));
    }
    bf16x8 a[4];
#pragma unroll
    for (int kb = 0; kb < 4; ++kb)
        a[kb] = *(const bf16x8*)&Aw[m16 * 136 + kb * 32 + q * 8];
    f32x4 acc[8];
#pragma unroll
    for (int t = 0; t < 8; ++t) {
        acc[t] = (f32x4){0.f, 0.f, 0.f, 0.f};
#pragma unroll
        for (int kb = 0; kb < 4; ++kb) {
            bf16x8 bfr = *(const bf16x8*)&Wl[(((kb * 4 + q) * 128) + t * 16 + m16) * 8];
            acc[t] = __builtin_amdgcn_mfma_f32_16x16x32_bf16(a[kb], bfr, acc[t], 0, 0, 0);
        }
    }
    __syncthreads();
    float* Ew = (float*)(lds + wv * 8448);
#pragma unroll
    for (int t = 0; t < 8; ++t)
#pragma unroll
        for (int r = 0; r < 4; ++r)
            Ew[(q * 4 + r) * 132 + t * 16 + m16] = acc[t][r];
    const int h  = lane >> 5;
    const int c4 = (lane & 31) << 2;
#pragma unroll
    for (int j = 0; j < 8; ++j) {
        int r = j * 2 + h;
        int node = nb + r;
        if (node < N_NODES) {
            float4 v  = *(const float4*)&Ew[r * 132 + c4];
            float4 xi = *(const float4*)(x + (size_t)node * D + c4);
            float4 o;
            o.x = fmaxf(v.x, 0.f) + xi.x;
            o.y = fmaxf(v.y, 0.f) + xi.y;
            o.z = fmaxf(v.z, 0.f) + xi.z;
            o.w = fmaxf(v.w, 0.f) + xi.w;
            *(float4*)(data + (size_t)node * D + c4) = o;
        }
    }
}

extern "C" void kernel_launch(void* const* d_in, const int* in_sizes, int n_in,
                              void* d_out, int out_size, void* d_ws, size_t ws_size,
                              hipStream_t stream) {
    const float* x   = (const float*)d_in[0];
    const int*   src = (const int*)d_in[1];   // harness passes integers as int32
    const int*   dst = (const int*)d_in[2];
    const float* W   = (const float*)d_in[3];
    float* out = (float*)d_out;

    char* ws = (char*)d_ws;
    int*    bcnt  = (int*)ws;        ws += (size_t)NBUCK * 4;
    ws = (char*)(((uintptr_t)ws + 15) & ~(uintptr_t)15);
    int*    pairs = (int*)ws;        ws += (size_t)NBUCK * BCAP * 4;
    ushort* xb    = (ushort*)ws;     ws += (size_t)N_NODES * D * 2;
    const bool big_ws = (ws_size >= (size_t)(ws - (char*)d_ws));

    if (big_ws) {
        hipMemsetAsync(bcnt, 0, (size_t)NBUCK * 4, stream);    // 3 KB fill
        convert_scatter<<<SCAT_BLOCKS, 1024, 0, stream>>>(     // 196 blocks
            (const float4*)x, xb, src, dst, bcnt, pairs);
        csr_gather_gemm<<<NBUCK, 256, 0, stream>>>(pairs, bcnt, xb, W, out);
    } else {
        // slow-but-correct fallback (no scratch needed beyond d_out)
        int n4 = N_NODES * D / 4;
        zero_out<<<(n4 + 255) / 256, 256, 0, stream>>>((float4*)out, n4);
        long long n_scatter = (long long)N_EDGES * 32;
        scatter_edges<<<(int)((n_scatter + 255) / 256), 256, 0, stream>>>(
            x, src, dst, out);
        gemm_relu_res_f32<<<(N_NODES + 63) / 64, 256, 0, stream>>>(out, W, x);
    }
}

// Round 2
// 137.337 us; speedup vs baseline: 1.1898x; 1.1898x over previous
//
#include <hip/hip_runtime.h>
#include <hip/hip_bf16.h>

#define N_NODES 50000
#define N_EDGES 800000
#define D 128

#define NBUCK 3125       // bucket = dst>>4 (16 nodes); 50000 = 3125*16 exactly
#define BCAP  512        // slots/bucket; count ~256 +/- ~16 (sd); 16-sd margin

#define SCAT_BLOCKS ((N_EDGES / 4 + 1023) / 1024)   // 196 — covers ALL edges

using bf16x8 = __attribute__((ext_vector_type(8))) short;   // 8 bf16 (4 VGPRs)
using u16x8  = __attribute__((ext_vector_type(8))) unsigned short;
using f32x4  = __attribute__((ext_vector_type(4))) float;   // MFMA C/D

static __device__ __forceinline__ ushort f2bf(float f) {
    __hip_bfloat16 h = __float2bfloat16(f);   // RNE
    return *reinterpret_cast<ushort*>(&h);
}
static __device__ __forceinline__ float bf2f(ushort u) {
    return __uint_as_float(((unsigned)u) << 16);
}

// ---------------------------------------------------------------------------
// ws layout (~19.3 MB): bcnt[NBUCK], pairs[NBUCK*BCAP] int, xb (bf16 x),
// wb (bf16 W, chunk-major [k/8][o][8], 32 KB — L1-resident in the GEMM).
// Fused per-bucket kernel granularity = 16 nodes so grid = 3125 blocks and
// LDS stays ~14 KB => ~7 blocks/CU (28 waves/CU) for gather latency hiding.
// ---------------------------------------------------------------------------

// Fused: x -> bf16 conversion (grid-stride) + W -> bf16 chunk-major + bucket
// scatter of edges.
__global__ void __launch_bounds__(1024)
convert_scatter(const float4* __restrict__ x4, ushort* __restrict__ xb,
                const float* __restrict__ W, ushort* __restrict__ wb,
                const int* __restrict__ src, const int* __restrict__ dst,
                int* __restrict__ bcnt, int* __restrict__ pairs) {
    __shared__ int lcnt[NBUCK], lbase[NBUCK];
    const int tid = threadIdx.x;
    for (int t0 = tid; t0 < NBUCK; t0 += 1024) lcnt[t0] = 0;

    // issue edge loads early (latency overlapped with conversion below)
    const int i = blockIdx.x * 1024 + tid;
    const bool valid = i < N_EDGES / 4;
    int4 s, d;
    if (valid) {
        s = ((const int4*)src)[i];
        d = ((const int4*)dst)[i];
    }

    // W -> bf16 chunk-major (blocks 0..1 only; 2048 chunks of 8)
    const int g = blockIdx.x * 1024 + tid;
    if (g < 2048) {
        int o  = g & 127;
        int kc = g >> 7;
        const float4* wp = (const float4*)(W + (size_t)o * D + kc * 8);
        float4 w0 = wp[0], w1 = wp[1];
        bf16x8 hv;
        hv[0] = (short)f2bf(w0.x); hv[1] = (short)f2bf(w0.y);
        hv[2] = (short)f2bf(w0.z); hv[3] = (short)f2bf(w0.w);
        hv[4] = (short)f2bf(w1.x); hv[5] = (short)f2bf(w1.y);
        hv[6] = (short)f2bf(w1.z); hv[7] = (short)f2bf(w1.w);
        *(bf16x8*)&wb[g * 8] = hv;
    }

    // streaming conversion: 1.6M float4, grid-stride over the actual grid
    const int total4 = N_NODES * D / 4;
    const int stride = gridDim.x * 1024;
    for (int j = blockIdx.x * 1024 + tid; j < total4; j += stride) {
        float4 v = x4[j];
        ushort4 u = make_ushort4(f2bf(v.x), f2bf(v.y), f2bf(v.z), f2bf(v.w));
        *(ushort4*)(xb + (size_t)j * 4) = u;
    }
    __syncthreads();          // lcnt zeros visible

    int bkt[4], slot[4];
    if (valid) {
        bkt[0] = d.x >> 4; slot[0] = atomicAdd(&lcnt[bkt[0]], 1);
        bkt[1] = d.y >> 4; slot[1] = atomicAdd(&lcnt[bkt[1]], 1);
        bkt[2] = d.z >> 4; slot[2] = atomicAdd(&lcnt[bkt[2]], 1);
        bkt[3] = d.w >> 4; slot[3] = atomicAdd(&lcnt[bkt[3]], 1);
    }
    __syncthreads();
    for (int t0 = tid; t0 < NBUCK; t0 += 1024) {
        int c = lcnt[t0];
        lbase[t0] = c ? atomicAdd(&bcnt[t0], c) : 0;
    }
    __syncthreads();
    if (valid) {
#pragma unroll
        for (int e = 0; e < 4; ++e) {
            int sv = (e == 0) ? s.x : (e == 1) ? s.y : (e == 2) ? s.z : s.w;
            int dv = (e == 0) ? d.x : (e == 1) ? d.y : (e == 2) ? d.z : d.w;
            int pos = lbase[bkt[e]] + slot[e];
            if (pos < BCAP)                       // ~16-sd guard, never trips
                pairs[bkt[e] * BCAP + pos] = sv | ((dv & 15) << 16);
        }
    }
}

// ---------------------------------------------------------------------------
// Fused per-bucket kernel: CSR-in-LDS -> gather to LDS agg tile -> MFMA GEMM
// + relu + residual. One block per 16-node bucket, 256 threads (4 waves).
// LDS 14016 B => ~7 blocks/CU (28 waves/CU). B-fragments read from global
// wb (32 KB bf16 W, L1-resident; 4x256B contiguous segments per frag load).
//   lsrc [512]     ushort              1024 B   (per-node-sorted src indices)
//   aggL [16][136] bf16 (pad 8)       4352 B   (agg rows; 16B-aligned rows)
//   Ew   [16][132] float              8448 B   (epilogue transpose)
//   lcnt2/lcur/lbeg [16] int each      192 B
// ---------------------------------------------------------------------------
__global__ void __launch_bounds__(256)
csr_gather_gemm(const int* __restrict__ pairs, const int* __restrict__ bcnt,
                const ushort* __restrict__ xb, const ushort* __restrict__ wb,
                float* __restrict__ out) {
    __shared__ __align__(16) char lds[14016];
    ushort* lsrc  = (ushort*)lds;                    //  1024 B
    ushort* aggL  = (ushort*)(lds + 1024);           //  4352 B
    float*  Ew    = (float*)(lds + 5376);            //  8448 B
    int*    lcnt2 = (int*)(lds + 13824);
    int*    lcur  = (int*)(lds + 13888);
    int*    lbeg  = (int*)(lds + 13952);

    const int b    = blockIdx.x;
    const int tid  = threadIdx.x;
    const int lane = tid & 63;
    const int wv   = tid >> 6;
    const int m16  = lane & 15;
    const int q    = lane >> 4;

    // ---- CSR in LDS: histogram -> wave-0 16-lane scan -> place ----
    const int base = b * BCAP;
    int n = bcnt[b];
    if (n > BCAP) n = BCAP;                          // 16-sd guard, never trips
    if (tid < 16) lcnt2[tid] = 0;
    __syncthreads();
    for (int i = tid; i < n; i += 256)
        atomicAdd(&lcnt2[pairs[base + i] >> 16], 1);
    __syncthreads();
    if (tid < 16) {                       // wave 0: 16-lane inclusive shfl scan
        int v = lcnt2[tid];
        int incl = v;
#pragma unroll
        for (int o = 1; o < 16; o <<= 1) {
            int t = __shfl_up(incl, o, 64);
            if (tid >= o) incl += t;
        }
        lbeg[tid] = incl - v;
        lcur[tid] = incl - v;
    }
    __syncthreads();
    for (int i = tid; i < n; i += 256) {
        int p = pairs[base + i];
        int pos = atomicAdd(&lcur[p >> 16], 1);
        lsrc[pos] = (ushort)(p & 0xFFFF);
    }
    __syncthreads();                      // lcur[t] == end(t) now

    // ---- gather: wave wv owns nodes wv*4 .. wv*4+3 (sequential) ----
    // Quarter-wave rows: 16 lanes x u16x8 (16B) = one full 256B bf16 row;
    // 4 rows/step; 4 steps in flight => 16 row-loads outstanding per wave.
    const int c8 = m16 << 3;               // bf16 col 0,8,..,120
    const ushort* xbb = xb + c8;
#pragma unroll 1
    for (int m = 0; m < 4; ++m) {
        const int nloc = wv * 4 + m;
        const int beg = lbeg[nloc], end = lcur[nloc];
        float acc[8];
#pragma unroll
        for (int j = 0; j < 8; ++j) acc[j] = 0.f;

        int t = beg;
        for (; t + 16 <= end; t += 16) {   // 16 rows in flight
            int s0 = lsrc[t + q];          // broadcast LDS read per quarter
            int s1 = lsrc[t + 4 + q];
            int s2 = lsrc[t + 8 + q];
            int s3 = lsrc[t + 12 + q];
            u16x8 u0 = *(const u16x8*)(xbb + (size_t)s0 * D);
            u16x8 u1 = *(const u16x8*)(xbb + (size_t)s1 * D);
            u16x8 u2 = *(const u16x8*)(xbb + (size_t)s2 * D);
            u16x8 u3 = *(const u16x8*)(xbb + (size_t)s3 * D);
#pragma unroll
            for (int j = 0; j < 8; ++j)
                acc[j] += (bf2f(u0[j]) + bf2f(u1[j])) + (bf2f(u2[j]) + bf2f(u3[j]));
        }
        for (; t + 4 <= end; t += 4) {
            int s = lsrc[t + q];
            u16x8 u = *(const u16x8*)(xbb + (size_t)s * D);
#pragma unroll
            for (int j = 0; j < 8; ++j) acc[j] += bf2f(u[j]);
        }
        const int rem = end - t;
        if (rem && q < rem) {
            int s = lsrc[t + q];
            u16x8 u = *(const u16x8*)(xbb + (size_t)s * D);
#pragma unroll
            for (int j = 0; j < 8; ++j) acc[j] += bf2f(u[j]);
        }
#pragma unroll
        for (int j = 0; j < 8; ++j) {
            acc[j] += __shfl_xor(acc[j], 16, 64);
            acc[j] += __shfl_xor(acc[j], 32, 64);
        }
        if (q == 0) {                      // row write: 16 lanes x 16B, 256B
            u16x8 u;
#pragma unroll
            for (int j = 0; j < 8; ++j) u[j] = f2bf(acc[j]);
            *(u16x8*)&aggL[(size_t)nloc * 136 + c8] = u;   // 272B rows, 16B-aligned
        }
    }
    __syncthreads();                       // aggL complete

    // ---- MFMA GEMM: out[n][o] = relu(sum_k agg[n][k]*W[o][k]) + x[n][o] ----
    // All waves share the same 16 A-rows; wave wv computes cols wv*32..wv*32+31.
    bf16x8 a[4];
#pragma unroll
    for (int kb = 0; kb < 4; ++kb)
        a[kb] = *(const bf16x8*)&aggL[(size_t)m16 * 136 + kb * 32 + q * 8];

    f32x4 acc[2];
#pragma unroll
    for (int tt = 0; tt < 2; ++tt) {
        const int t = wv * 2 + tt;
        acc[tt] = (f32x4){0.f, 0.f, 0.f, 0.f};
#pragma unroll
        for (int kb = 0; kb < 4; ++kb) {
            bf16x8 bfr = *(const bf16x8*)&wb[(((kb * 4 + q) * 128) + t * 16 + m16) * 8];
            acc[tt] = __builtin_amdgcn_mfma_f32_16x16x32_bf16(a[kb], bfr, acc[tt], 0, 0, 0);
        }
    }

#pragma unroll
    for (int tt = 0; tt < 2; ++tt) {
        const int t = wv * 2 + tt;
#pragma unroll
        for (int r = 0; r < 4; ++r)
            Ew[(q * 4 + r) * 132 + t * 16 + m16] = acc[tt][r];
    }
    __syncthreads();                       // Ew complete (cross-wave cols)

    // ---- epilogue: relu + residual, 2 float4 per thread, coalesced ----
#pragma unroll
    for (int k = 0; k < 2; ++k) {
        int idx = tid + k * 256;
        int row = idx >> 5;                // 0..15
        int c4  = (idx & 31) << 2;         // f32 col 0,4,..,124
        int node = b * 16 + row;           // < 50000 always (3125*16 exact)
        float4 v  = *(const float4*)&Ew[row * 132 + c4];
        ushort4 xu = *(const ushort4*)(xb + (size_t)node * D + c4);
        float4 o;
        o.x = fmaxf(v.x, 0.f) + bf2f(xu.x);
        o.y = fmaxf(v.y, 0.f) + bf2f(xu.y);
        o.z = fmaxf(v.z, 0.f) + bf2f(xu.z);
        o.w = fmaxf(v.w, 0.f) + bf2f(xu.w);
        *(float4*)(out + (size_t)node * D + c4) = o;
    }
}

// ===================== minimal fallback (tiny ws; never expected) ==========
__global__ void zero_out(float4* __restrict__ p, int n4) {
    int i = blockIdx.x * 256 + threadIdx.x;
    if (i < n4) p[i] = make_float4(0.f, 0.f, 0.f, 0.f);
}
__global__ void scatter_edges(const float* __restrict__ x,
                              const int* __restrict__ src,
                              const int* __restrict__ dst,
                              float* __restrict__ agg) {
    long long tid = (long long)blockIdx.x * 256 + threadIdx.x;
    if (tid >= (long long)N_EDGES * 32) return;
    int edge = (int)(tid >> 5);
    int c    = ((int)tid & 31) << 2;
    const float4 v = *(const float4*)(x + (size_t)src[edge] * D + c);
    float* p = agg + (size_t)dst[edge] * D + c;
    unsafeAtomicAdd(p + 0, v.x);
    unsafeAtomicAdd(p + 1, v.y);
    unsafeAtomicAdd(p + 2, v.z);
    unsafeAtomicAdd(p + 3, v.w);
}
__global__ void __launch_bounds__(256)
gemm_relu_res_f32(float* data, const float* __restrict__ W,
                  const float* __restrict__ x) {
    __shared__ __align__(16) char lds[50176];
    ushort* Wl = (ushort*)lds;
    ushort* Al = (ushort*)(lds + 32768);
    const int tid  = threadIdx.x;
    const int lane = tid & 63;
    const int wv   = tid >> 6;
    const int m16  = lane & 15;
    const int q    = lane >> 4;
#pragma unroll
    for (int i = 0; i < 8; ++i) {
        int g  = tid + i * 256;
        int o  = g & 127;
        int kc = g >> 7;
        const float4* wp = (const float4*)(W + (size_t)o * D + kc * 8);
        float4 w0 = wp[0], w1 = wp[1];
        bf16x8 hv;
        hv[0] = (short)f2bf(w0.x); hv[1] = (short)f2bf(w0.y);
        hv[2] = (short)f2bf(w0.z); hv[3] = (short)f2bf(w0.w);
        hv[4] = (short)f2bf(w1.x); hv[5] = (short)f2bf(w1.y);
        hv[6] = (short)f2bf(w1.z); hv[7] = (short)f2bf(w1.w);
        *(bf16x8*)&Wl[g * 8] = hv;
    }
    __syncthreads();
    const int nb = blockIdx.x * 64 + wv * 16;
    ushort* Aw = &Al[wv * (16 * 136)];
#pragma unroll
    for (int m = 0; m < 16; ++m) {
        int node = nb + m;
        float2 v = make_float2(0.f, 0.f);
        if (node < N_NODES)
            v = *(const float2*)(data + (size_t)node * D + lane * 2);
        *(ushort2*)&Aw[m * 136 + lane * 2] = make_ushort2(f2bf(v.x), f2bf(v.y));
    }
    bf16x8 a[4];
#pragma unroll
    for (int kb = 0; kb < 4; ++kb)
        a[kb] = *(const bf16x8*)&Aw[m16 * 136 + kb * 32 + q * 8];
    f32x4 acc[8];
#pragma unroll
    for (int t = 0; t < 8; ++t) {
        acc[t] = (f32x4){0.f, 0.f, 0.f, 0.f};
#pragma unroll
        for (int kb = 0; kb < 4; ++kb) {
            bf16x8 bfr = *(const bf16x8*)&Wl[(((kb * 4 + q) * 128) + t * 16 + m16) * 8];
            acc[t] = __builtin_amdgcn_mfma_f32_16x16x32_bf16(a[kb], bfr, acc[t], 0, 0, 0);
        }
    }
    __syncthreads();
    float* Ew = (float*)(lds + wv * 8448);
#pragma unroll
    for (int t = 0; t < 8; ++t)
#pragma unroll
        for (int r = 0; r < 4; ++r)
            Ew[(q * 4 + r) * 132 + t * 16 + m16] = acc[t][r];
    const int h  = lane >> 5;
    const int c4 = (lane & 31) << 2;
#pragma unroll
    for (int j = 0; j < 8; ++j) {
        int r = j * 2 + h;
        int node = nb + r;
        if (node < N_NODES) {
            float4 v  = *(const float4*)&Ew[r * 132 + c4];
            float4 xi = *(const float4*)(x + (size_t)node * D + c4);
            float4 o;
            o.x = fmaxf(v.x, 0.f) + xi.x;
            o.y = fmaxf(v.y, 0.f) + xi.y;
            o.z = fmaxf(v.z, 0.f) + xi.z;
            o.w = fmaxf(v.w, 0.f) + xi.w;
            *(float4*)(data + (size_t)node * D + c4) = o;
        }
    }
}

extern "C" void kernel_launch(void* const* d_in, const int* in_sizes, int n_in,
                              void* d_out, int out_size, void* d_ws, size_t ws_size,
                              hipStream_t stream) {
    const float* x   = (const float*)d_in[0];
    const int*   src = (const int*)d_in[1];   // harness passes integers as int32
    const int*   dst = (const int*)d_in[2];
    const float* W   = (const float*)d_in[3];
    float* out = (float*)d_out;

    char* ws = (char*)d_ws;
    int*    bcnt  = (int*)ws;        ws += (size_t)NBUCK * 4;
    ws = (char*)(((uintptr_t)ws + 15) & ~(uintptr_t)15);
    int*    pairs = (int*)ws;        ws += (size_t)NBUCK * BCAP * 4;
    ushort* xb    = (ushort*)ws;     ws += (size_t)N_NODES * D * 2;
    ushort* wb    = (ushort*)ws;     ws += (size_t)D * D * 2;
    const bool big_ws = (ws_size >= (size_t)(ws - (char*)d_ws));

    if (big_ws) {
        hipMemsetAsync(bcnt, 0, (size_t)NBUCK * 4, stream);    // 12.5 KB fill
        convert_scatter<<<SCAT_BLOCKS, 1024, 0, stream>>>(     // 196 blocks
            (const float4*)x, xb, W, wb, src, dst, bcnt, pairs);
        csr_gather_gemm<<<NBUCK, 256, 0, stream>>>(pairs, bcnt, xb, wb, out);
    } else {
        // slow-but-correct fallback (no scratch needed beyond d_out)
        int n4 = N_NODES * D / 4;
        zero_out<<<(n4 + 255) / 256, 256, 0, stream>>>((float4*)out, n4);
        long long n_scatter = (long long)N_EDGES * 32;
        scatter_edges<<<(int)((n_scatter + 255) / 256), 256, 0, stream>>>(
            x, src, dst, out);
        gemm_relu_res_f32<<<(N_NODES + 63) / 64, 256, 0, stream>>>(out, W, x);
    }
}